// Round 4
// 862.645 us; speedup vs baseline: 1.1322x; 1.1322x over previous
//
#include <hip/hip_runtime.h>
#include <hip/hip_bf16.h>

// ReAttention fused pipeline, bf16 MFMA throughout.
// Design notes:
//  - softmax without max-subtraction (scores std ~0.3; exp2-based, log2e folded into q scale)
//  - BN mean analytic (softmax rows sum to 1); BN var from 12x12 cross-moment C (MFMA)
//  - pre-BN mixed attn never materialized
//  - BN+head-mix folded into one MFMA: attn_norm = W2 @ P + c2
// R1 fix: GEMM LDS staging covered only half the 128x32 tile. Fixed.
// R5: resubmit of R3/R4 source (3 consecutive container-level failures, error is
//     acquire/run wrapper not a pytest verdict; source audited 3x, no OOB / no
//     divergent barrier / no data-dependent loop -> environmental).
//     GEMMs: R0-verified reg-staged path. attn_stats: single-sweep rewrite:
//  (b) SINGLE QK^T sweep. C_gh = sum_n invl_g*invl_h*M_gh[n] with unnormalized
//      per-row moments M_gh[n] = sum_m E_g E_h accumulated per-n in AGPRs (16 MFMA accs).
//      Removes 2nd score sweep (12 MFMA + 24 exp2/iter), halves K streaming.
//  (c) rsum shuffle-reduction deferred to after the m-loop (1x instead of 32x)
//  (d) Cmat atomics: block-level LDS reduce first -> 4x fewer global atomics

typedef __attribute__((ext_vector_type(8))) short s16x8;   // 8 x bf16 (4 VGPRs) MFMA operand
typedef __attribute__((ext_vector_type(4))) float f32x4;

#define QK_SCALE 0.18033688011112042f  // 0.125 * log2(e)

__device__ __forceinline__ f32x4 mfma16(s16x8 a, s16x8 b, f32x4 c) {
    return __builtin_amdgcn_mfma_f32_16x16x32_bf16(a, b, c, 0, 0, 0);
}

__device__ __forceinline__ unsigned short f2bf(float f) {
    unsigned u = __float_as_uint(f);
    u += 0x7fffu + ((u >> 16) & 1u);   // RNE
    return (unsigned short)(u >> 16);
}

// ---------------- fp32 -> bf16 convert ----------------
__global__ __launch_bounds__(256) void cvt_bf16_k(const float* __restrict__ in,
                                                  unsigned short* __restrict__ out, int n4) {
    int i = blockIdx.x * 256 + threadIdx.x;
    if (i < n4) {
        float4 v = ((const float4*)in)[i];
        ushort4 o;
        o.x = f2bf(v.x); o.y = f2bf(v.y); o.z = f2bf(v.z); o.w = f2bf(v.w);
        ((ushort4*)out)[i] = o;
    }
}

// ---------------- QKV GEMM: [8192x768] @ [2304x768]^T + bias -> q,k,v [B,H,N,D] bf16 ----------------
__global__ __launch_bounds__(256) void gemm_qkv_k(
    const unsigned short* __restrict__ A,   // xb [8192][768]
    const unsigned short* __restrict__ Bw,  // wqb [2304][768]
    const float* __restrict__ bias,         // [2304]
    unsigned short* __restrict__ qs, unsigned short* __restrict__ ks,
    unsigned short* __restrict__ vs)
{
    __shared__ unsigned short Al[128 * 32];
    __shared__ unsigned short Bl[128 * 32];
    const int tid = threadIdx.x, wv = tid >> 6, ln = tid & 63;
    const int r = ln & 15, q = ln >> 4;
    const int i0 = blockIdx.y * 128, j0 = blockIdx.x * 128;
    const int wm = (wv & 1) * 64, wn = (wv >> 1) * 64;
    const int srow = tid >> 2, scol = (tid & 3) * 8;   // 64 rows x 32 cols per pass, 2 passes
    f32x4 acc[4][4] = {};
    for (int kb = 0; kb < 768; kb += 32) {
        s16x8 av0 = *(const s16x8*)(A  + (size_t)(i0 + srow) * 768 + kb + scol);
        s16x8 av1 = *(const s16x8*)(A  + (size_t)(i0 + srow + 64) * 768 + kb + scol);
        s16x8 bv0 = *(const s16x8*)(Bw + (size_t)(j0 + srow) * 768 + kb + scol);
        s16x8 bv1 = *(const s16x8*)(Bw + (size_t)(j0 + srow + 64) * 768 + kb + scol);
        __syncthreads();
        *(s16x8*)(Al + srow * 32 + scol)        = av0;
        *(s16x8*)(Al + (srow + 64) * 32 + scol) = av1;
        *(s16x8*)(Bl + srow * 32 + scol)        = bv0;
        *(s16x8*)(Bl + (srow + 64) * 32 + scol) = bv1;
        __syncthreads();
        s16x8 af[4], bf[4];
#pragma unroll
        for (int mt = 0; mt < 4; mt++) af[mt] = *(const s16x8*)(Al + (wm + mt * 16 + r) * 32 + q * 8);
#pragma unroll
        for (int nt = 0; nt < 4; nt++) bf[nt] = *(const s16x8*)(Bl + (wn + nt * 16 + r) * 32 + q * 8);
#pragma unroll
        for (int mt = 0; mt < 4; mt++)
#pragma unroll
            for (int nt = 0; nt < 4; nt++)
                acc[mt][nt] = mfma16(af[mt], bf[nt], acc[mt][nt]);
    }
#pragma unroll
    for (int nt = 0; nt < 4; nt++) {
        int j = j0 + wn + nt * 16 + r;                 // column in [0,2304): (t,h,d)
        int t = (j >= 1536) ? 2 : (j >= 768 ? 1 : 0);
        int rem = j - t * 768;
        int h = rem >> 6, d = rem & 63;
        float bb = bias[j];
#pragma unroll
        for (int mt = 0; mt < 4; mt++) {
#pragma unroll
            for (int rr = 0; rr < 4; rr++) {
                int i = i0 + wm + mt * 16 + q * 4 + rr;  // row = (b,n)
                int bidx = i >> 10, n = i & 1023;
                float val = acc[mt][nt][rr] + bb;
                size_t off = (((size_t)bidx * 12 + h) * 1024 + n) * 64 + d;
                if (t == 0)      qs[off] = f2bf(val * QK_SCALE);  // fold softmax scale+log2e into q
                else if (t == 1) ks[off] = f2bf(val);
                else             vs[off] = f2bf(val);
            }
        }
    }
}

// ---------------- v [BH][N][D] -> vT [BH][D][N] ----------------
__global__ __launch_bounds__(256) void transpose_v_k(const unsigned short* __restrict__ vs,
                                                     unsigned short* __restrict__ vT)
{
    __shared__ unsigned short t[64][65];
    const int tid = threadIdx.x;
    const int bh = blockIdx.x;
    const int n0 = blockIdx.y * 64;
    const unsigned short* src = vs + ((size_t)bh * 1024 + n0) * 64;
#pragma unroll
    for (int i = 0; i < 4; i++) {
        int id4 = tid + i * 256;
        int row = id4 >> 4, c4 = (id4 & 15) * 4;
        ushort4 v = *(const ushort4*)(src + row * 64 + c4);
        t[row][c4 + 0] = v.x; t[row][c4 + 1] = v.y; t[row][c4 + 2] = v.z; t[row][c4 + 3] = v.w;
    }
    __syncthreads();
#pragma unroll
    for (int i = 0; i < 4; i++) {
        int id4 = tid + i * 256;
        int d = id4 >> 4, c4 = (id4 & 15) * 4;
        ushort4 o;
        o.x = t[c4 + 0][d]; o.y = t[c4 + 1][d]; o.z = t[c4 + 2][d]; o.w = t[c4 + 3][d];
        *(ushort4*)(vT + ((size_t)bh * 64 + d) * 1024 + n0 + c4) = o;
    }
}

// ---------------- attention pass 1 (SINGLE sweep): row sums (invL) + cross-moment C ----------------
// C_gh = sum_{b,n} invl_g[b,n] invl_h[b,n] M_gh[b,n],  M_gh[n] = sum_m E_g[n,m] E_h[n,m]
// (E = unnormalized exp scores). M accumulated per-n via 16 MFMA accumulators, invl applied at end.
__global__ __launch_bounds__(256) void attn_stats_k(
    const unsigned short* __restrict__ qs, const unsigned short* __restrict__ ks,
    float* __restrict__ Lbuf, float* __restrict__ Cmat)
{
    // Et: [n(16)][h(16, rows 12..15 stay zero)][m(32)]; padded strides: h->34, n->546
    __shared__ unsigned short Et[16 * 546];
    __shared__ float invLt[16][17];
    __shared__ float Cred[256];
    const int tid = threadIdx.x, wv = tid >> 6, ln = tid & 63;
    const int r = ln & 15, q = ln >> 4;
    const int b = blockIdx.x >> 6, n0 = (blockIdx.x & 63) * 16;
    const size_t bh0 = (size_t)b * 12;

    for (int i = tid; i < 16 * 546; i += 256) Et[i] = 0;
    for (int i = tid; i < 272; i += 256) (&invLt[0][0])[i] = 0.f;
    Cred[tid] = 0.f;

    s16x8 qf[3][2];
#pragma unroll
    for (int hh = 0; hh < 3; hh++) {
        int h = wv * 3 + hh;
        const unsigned short* qp = qs + ((bh0 + h) * 1024 + n0 + r) * 64 + q * 8;
        qf[hh][0] = *(const s16x8*)qp;
        qf[hh][1] = *(const s16x8*)(qp + 32);
    }
    float rsum[3][4] = {};
    f32x4 Macc[4] = {};   // per-row moments, this wave owns rows n = wv*4 + t
    __syncthreads();      // Et/invLt/Cred init visible before first use

    for (int m0 = 0; m0 < 1024; m0 += 32) {
#pragma unroll
        for (int hh = 0; hh < 3; hh++) {
            int h = wv * 3 + hh;
            const unsigned short* kp = ks + (bh0 + h) * 65536;
            f32x4 sc0 = {0,0,0,0}, sc1 = {0,0,0,0};
#pragma unroll
            for (int s = 0; s < 2; s++) {
                s16x8 k0 = *(const s16x8*)(kp + (size_t)(m0 + r) * 64 + s * 32 + q * 8);
                s16x8 k1 = *(const s16x8*)(kp + (size_t)(m0 + 16 + r) * 64 + s * 32 + q * 8);
                sc0 = mfma16(qf[hh][s], k0, sc0);
                sc1 = mfma16(qf[hh][s], k1, sc1);
            }
#pragma unroll
            for (int rr = 0; rr < 4; rr++) {
                float e0 = exp2f(sc0[rr]), e1 = exp2f(sc1[rr]);
                rsum[hh][rr] += e0 + e1;            // per-lane partial (m = r mod 16), reduce later
                int base = (q * 4 + rr) * 546 + h * 34;
                Et[base + r]      = f2bf(e0);
                Et[base + 16 + r] = f2bf(e1);
            }
        }
        __syncthreads();
        // M_gh[n] += E E^T over this 32-m slab: A-frag == B-frag (symmetric)
#pragma unroll
        for (int t = 0; t < 4; t++) {
            s16x8 ef = *(const s16x8*)(Et + (wv * 4 + t) * 546 + r * 34 + q * 8);
            Macc[t] = mfma16(ef, ef, Macc[t]);
        }
        __syncthreads();
    }
    // finalize invl (one butterfly instead of 32), write Lbuf + invLt
#pragma unroll
    for (int hh = 0; hh < 3; hh++)
#pragma unroll
        for (int rr = 0; rr < 4; rr++) {
            float v = rsum[hh][rr];
#pragma unroll
            for (int msk = 8; msk; msk >>= 1) v += __shfl_xor(v, msk, 16);
            float iv = 1.0f / v;
            if (r == 0) {
                Lbuf[(bh0 + wv * 3 + hh) * 1024 + n0 + q * 4 + rr] = iv;
                invLt[q * 4 + rr][wv * 3 + hh] = iv;
            }
        }
    __syncthreads();
    // C_lane[g=q*4+rr][h'=r] += invl_g[n] * invl_h'[n] * M[n]
    float cl[4] = {0.f, 0.f, 0.f, 0.f};
#pragma unroll
    for (int t = 0; t < 4; t++) {
        int n = wv * 4 + t;
        float ih = invLt[n][r];
#pragma unroll
        for (int rr = 0; rr < 4; rr++)
            cl[rr] += invLt[n][q * 4 + rr] * ih * Macc[t][rr];
    }
    // block-level reduce in LDS, then one global atomic per slot per block
#pragma unroll
    for (int rr = 0; rr < 4; rr++)
        atomicAdd(&Cred[(q * 4 + rr) * 16 + r], cl[rr]);
    __syncthreads();
    if (Cred[tid] != 0.f) atomicAdd(&Cmat[tid], Cred[tid]);
}

// ---------------- BN stats finalize -> folded W2 (bf16, padded [16][32]) and c2 ----------------
__global__ void bn_stats_k(const float* __restrict__ Cmat,
                           const float* __restrict__ w_re, const float* __restrict__ b_re,
                           const float* __restrict__ gamma, const float* __restrict__ beta,
                           unsigned short* __restrict__ W2, float* __restrict__ c2)
{
    __shared__ float Cs[12][12];
    int tid = threadIdx.x;
    if (tid < 144) Cs[tid / 12][tid % 12] = Cmat[(tid / 12) * 16 + (tid % 12)];
    __syncthreads();
    if (tid < 16) {
        for (int hc = 0; hc < 32; hc++) W2[tid * 32 + hc] = 0;
        if (tid >= 12) c2[tid] = 0.f;
    }
    if (tid < 12) {
        const float S1 = 8192.f;        // sum of P over all (b,n,m) per head (rows sum to 1)
        const float cnt = 8388608.f;    // B*N*N
        float wg[12];
        for (int h = 0; h < 12; h++) wg[h] = w_re[tid * 12 + h];
        float bg = b_re[tid];
        float sw = 0.f;
        for (int h = 0; h < 12; h++) sw += wg[h];
        float mean = sw * (S1 / cnt) + bg;
        float q2 = 0.f;
        for (int h = 0; h < 12; h++)
            for (int h2 = 0; h2 < 12; h2++) q2 += wg[h] * wg[h2] * Cs[h][h2];
        float sumsq = q2 + 2.f * bg * sw * S1 + cnt * bg * bg;
        float var = sumsq / cnt - mean * mean;
        float scale = gamma[tid] * rsqrtf(var + 1e-5f);
        c2[tid] = beta[tid] - mean * scale + scale * bg;
        for (int h = 0; h < 12; h++) W2[tid * 32 + h] = f2bf(scale * wg[h]);
    }
}

// ---------------- pass 2: scores -> P -> mix(W2)+c2 -> write attn + PV -> out_head ----------------
__global__ __launch_bounds__(256) void attn_out_k(
    const unsigned short* __restrict__ qs, const unsigned short* __restrict__ ks,
    const unsigned short* __restrict__ vT, const float* __restrict__ Lbuf,
    const unsigned short* __restrict__ W2, const float* __restrict__ c2,
    float* __restrict__ attnO, unsigned short* __restrict__ oh)
{
    __shared__ unsigned short P[512][32];      // [pt][h-slot(32)], hblock XOR-swizzled by pt
    __shared__ unsigned short AT[12][16][40];  // normalized attn tile [g][n][m(pad)] for PV A-frags
    const int tid = threadIdx.x, wv = tid >> 6, ln = tid & 63;
    const int r = ln & 15, q = ln >> 4;
    const int b = blockIdx.x >> 6, n0 = (blockIdx.x & 63) * 16;
    const size_t bh0 = (size_t)b * 12;

    for (int i = tid; i < 512 * 32; i += 256) ((unsigned short*)P)[i] = 0;

    s16x8 qf[3][2];
    float invl[3][4];
#pragma unroll
    for (int hh = 0; hh < 3; hh++) {
        int h = wv * 3 + hh;
        const unsigned short* qp = qs + ((bh0 + h) * 1024 + n0 + r) * 64 + q * 8;
        qf[hh][0] = *(const s16x8*)qp;
        qf[hh][1] = *(const s16x8*)(qp + 32);
#pragma unroll
        for (int rr = 0; rr < 4; rr++)
            invl[hh][rr] = Lbuf[(bh0 + h) * 1024 + n0 + q * 4 + rr];
    }
    s16x8 w2f = *(const s16x8*)(W2 + r * 32 + q * 8);  // A[g=lane&15][h=q*8+j]
    float c2v[4];
#pragma unroll
    for (int rr = 0; rr < 4; rr++) c2v[rr] = c2[q * 4 + rr];
    f32x4 pv[3][4] = {};
    __syncthreads();

    for (int m0 = 0; m0 < 1024; m0 += 32) {
        // scores + P scatter
#pragma unroll
        for (int hh = 0; hh < 3; hh++) {
            int h = wv * 3 + hh;
            const unsigned short* kp = ks + (bh0 + h) * 1024 * 64;
            f32x4 sc0 = {0,0,0,0}, sc1 = {0,0,0,0};
#pragma unroll
            for (int s = 0; s < 2; s++) {
                s16x8 k0 = *(const s16x8*)(kp + (size_t)(m0 + r) * 64 + s * 32 + q * 8);
                s16x8 k1 = *(const s16x8*)(kp + (size_t)(m0 + 16 + r) * 64 + s * 32 + q * 8);
                sc0 = mfma16(qf[hh][s], k0, sc0);
                sc1 = mfma16(qf[hh][s], k1, sc1);
            }
            int hb = h >> 3, hl = h & 7;
#pragma unroll
            for (int rr = 0; rr < 4; rr++) {
                int pt0 = (q * 4 + rr) * 32 + r;
                int pt1 = pt0 + 16;
                P[pt0][((hb + pt0) & 3) * 8 + hl] = f2bf(exp2f(sc0[rr]) * invl[hh][rr]);
                P[pt1][((hb + pt1) & 3) * 8 + hl] = f2bf(exp2f(sc1[rr]) * invl[hh][rr]);
            }
        }
        __syncthreads();
        // mix: attn_norm[g][pt] = W2 @ P + c2; write to d_out + stage into AT
#pragma unroll
        for (int t = 0; t < 8; t++) {
            int pt = wv * 128 + t * 16 + r;
            s16x8 pf = *(const s16x8*)(&P[pt][((q + pt) & 3) * 8]);
            f32x4 d = mfma16(w2f, pf, f32x4{0, 0, 0, 0});
            int n = pt >> 5, m = pt & 31;
#pragma unroll
            for (int rr = 0; rr < 4; rr++) {
                int g = q * 4 + rr;
                if (g < 12) {
                    float av = d[rr] + c2v[rr];
                    attnO[((bh0 + g) * 1024 + n0 + n) * 1024 + m0 + m] = av;
                    AT[g][n][m] = f2bf(av);
                }
            }
        }
        __syncthreads();
        // PV: out[g][n][d] += attn_norm @ v  (vT gives contiguous B-frags)
#pragma unroll
        for (int hh = 0; hh < 3; hh++) {
            int g = wv * 3 + hh;
            s16x8 af = *(const s16x8*)(&AT[g][r][q * 8]);
            const unsigned short* vp = vT + (bh0 + g) * 64 * 1024;
#pragma unroll
            for (int dt = 0; dt < 4; dt++) {
                s16x8 vf = *(const s16x8*)(vp + (size_t)(dt * 16 + r) * 1024 + m0 + q * 8);
                pv[hh][dt] = mfma16(af, vf, pv[hh][dt]);
            }
        }
        __syncthreads();
    }
    // epilogue: out_head bf16 [b][n][h*64+d]  (proj-ready layout)
#pragma unroll
    for (int hh = 0; hh < 3; hh++) {
        int h = wv * 3 + hh;
#pragma unroll
        for (int dt = 0; dt < 4; dt++) {
#pragma unroll
            for (int rr = 0; rr < 4; rr++) {
                int n = n0 + q * 4 + rr;
                oh[((size_t)b * 1024 + n) * 768 + h * 64 + dt * 16 + r] = f2bf(pv[hh][dt][rr]);
            }
        }
    }
}

// ---------------- proj GEMM: oh [8192x768] @ w_proj^T + bias -> out fp32 ----------------
__global__ __launch_bounds__(256) void gemm_proj_k(
    const unsigned short* __restrict__ A,   // oh [8192][768]
    const unsigned short* __restrict__ Bw,  // wpb [768][768]
    const float* __restrict__ bias, float* __restrict__ Co)
{
    __shared__ unsigned short Al[128 * 32];
    __shared__ unsigned short Bl[128 * 32];
    const int tid = threadIdx.x, wv = tid >> 6, ln = tid & 63;
    const int r = ln & 15, q = ln >> 4;
    const int i0 = blockIdx.y * 128, j0 = blockIdx.x * 128;
    const int wm = (wv & 1) * 64, wn = (wv >> 1) * 64;
    const int srow = tid >> 2, scol = (tid & 3) * 8;   // full 128x32 tile coverage
    f32x4 acc[4][4] = {};
    for (int kb = 0; kb < 768; kb += 32) {
        s16x8 av0 = *(const s16x8*)(A  + (size_t)(i0 + srow) * 768 + kb + scol);
        s16x8 av1 = *(const s16x8*)(A  + (size_t)(i0 + srow + 64) * 768 + kb + scol);
        s16x8 bv0 = *(const s16x8*)(Bw + (size_t)(j0 + srow) * 768 + kb + scol);
        s16x8 bv1 = *(const s16x8*)(Bw + (size_t)(j0 + srow + 64) * 768 + kb + scol);
        __syncthreads();
        *(s16x8*)(Al + srow * 32 + scol)        = av0;
        *(s16x8*)(Al + (srow + 64) * 32 + scol) = av1;
        *(s16x8*)(Bl + srow * 32 + scol)        = bv0;
        *(s16x8*)(Bl + (srow + 64) * 32 + scol) = bv1;
        __syncthreads();
        s16x8 af[4], bf[4];
#pragma unroll
        for (int mt = 0; mt < 4; mt++) af[mt] = *(const s16x8*)(Al + (wm + mt * 16 + r) * 32 + q * 8);
#pragma unroll
        for (int nt = 0; nt < 4; nt++) bf[nt] = *(const s16x8*)(Bl + (wn + nt * 16 + r) * 32 + q * 8);
#pragma unroll
        for (int mt = 0; mt < 4; mt++)
#pragma unroll
            for (int nt = 0; nt < 4; nt++)
                acc[mt][nt] = mfma16(af[mt], bf[nt], acc[mt][nt]);
    }
#pragma unroll
    for (int nt = 0; nt < 4; nt++) {
        int j = j0 + wn + nt * 16 + r;
        float bb = bias[j];
#pragma unroll
        for (int mt = 0; mt < 4; mt++) {
#pragma unroll
            for (int rr = 0; rr < 4; rr++) {
                int i = i0 + wm + mt * 16 + q * 4 + rr;
                Co[(size_t)i * 768 + j] = acc[mt][nt][rr] + bb;
            }
        }
    }
}

extern "C" void kernel_launch(void* const* d_in, const int* in_sizes, int n_in,
                              void* d_out, int out_size, void* d_ws, size_t ws_size,
                              hipStream_t stream)
{
    const float* x      = (const float*)d_in[0];
    const float* w_qkv  = (const float*)d_in[1];
    const float* b_qkv  = (const float*)d_in[2];
    const float* w_re   = (const float*)d_in[3];
    const float* b_re   = (const float*)d_in[4];
    const float* gamma  = (const float*)d_in[5];
    const float* beta   = (const float*)d_in[6];
    const float* w_proj = (const float*)d_in[7];
    const float* b_proj = (const float*)d_in[8];

    float* outp  = (float*)d_out;
    float* attnp = outp + 6291456;   // out (8,1024,768) then attn (8,12,1024,1024)

    char* ws = (char*)d_ws;
    unsigned short* xb  = (unsigned short*)(ws);              // 12.58 MB (reused as oh later)
    unsigned short* wqb = (unsigned short*)(ws + 12582912);   // 3.54 MB
    unsigned short* wpb = (unsigned short*)(ws + 16121856);   // 1.18 MB
    unsigned short* qs  = (unsigned short*)(ws + 17301504);   // 12.58 MB
    unsigned short* ks  = (unsigned short*)(ws + 29884416);   // 12.58 MB
    unsigned short* vs  = (unsigned short*)(ws + 42467328);   // 12.58 MB
    unsigned short* vT  = (unsigned short*)(ws + 55050240);   // 12.58 MB
    float* Lbuf         = (float*)(ws + 67633152);            // 393 KB (invL)
    float* Cmat         = (float*)(ws + 68026368);            // 1 KB
    unsigned short* W2  = (unsigned short*)(ws + 68027392);   // 1 KB
    float* c2           = (float*)(ws + 68028416);            // 64 B
    unsigned short* oh  = xb;  // out_head overlays xb (xb dead after QKV GEMM)

    hipMemsetAsync(Cmat, 0, 1024, stream);
    cvt_bf16_k<<<6144, 256, 0, stream>>>(x,      xb,  1572864);
    cvt_bf16_k<<<1728, 256, 0, stream>>>(w_qkv,  wqb, 442368);
    cvt_bf16_k<<<576,  256, 0, stream>>>(w_proj, wpb, 147456);
    gemm_qkv_k<<<dim3(18, 64), 256, 0, stream>>>(xb, wqb, b_qkv, qs, ks, vs);
    transpose_v_k<<<dim3(96, 16), 256, 0, stream>>>(vs, vT);
    attn_stats_k<<<512, 256, 0, stream>>>(qs, ks, Lbuf, Cmat);
    bn_stats_k<<<1, 256, 0, stream>>>(Cmat, w_re, b_re, gamma, beta, W2, c2);
    attn_out_k<<<512, 256, 0, stream>>>(qs, ks, vT, Lbuf, W2, c2, attnp, oh);
    gemm_proj_k<<<dim3(6, 64), 256, 0, stream>>>(oh, wpb, b_proj, outp);
}

// Round 5
// 831.654 us; speedup vs baseline: 1.1744x; 1.0373x over previous
//
#include <hip/hip_runtime.h>
#include <hip/hip_bf16.h>

// ReAttention fused pipeline, bf16 MFMA throughout.
// Design notes:
//  - softmax without max-subtraction (scores std ~0.3; exp2-based, log2e folded into q scale)
//  - BN mean analytic (softmax rows sum to 1); BN var from 12x12 cross-moment C (MFMA)
//  - pre-BN mixed attn never materialized
//  - BN+head-mix folded into one MFMA
// R4 (862 us): single-sweep attn_stats (C from unnormalized moments M, invl post-hoc).
// R5: vectorize the scalar scatter/store tails via MFMA operand-order swaps:
//  (a) attn_out mix: mfma(P,W2) instead of mfma(W2,P) -> lane holds 4 consecutive m at
//      fixed g=r -> float4 attn stores (32 dwords -> 8 dwordx4 /lane/iter) and b64 AT
//      stores (32 b16 -> 8 b64). AT g-padded (648-short stride) for bank spread.
//  (b) attn_stats QK^T: mfma(K,Q) instead of mfma(Q,K) -> lane holds (n=r, 4 consecutive m)
//      -> Et scatter 24 b16 -> 6 b64 writes/lane/iter into [h][n][m] layout (h-stride 580),
//      rsum reduce 4 shuffle steps -> 2.

typedef __attribute__((ext_vector_type(8))) short s16x8;   // 8 x bf16 (4 VGPRs) MFMA operand
typedef __attribute__((ext_vector_type(4))) float f32x4;

#define QK_SCALE 0.18033688011112042f  // 0.125 * log2(e)

__device__ __forceinline__ f32x4 mfma16(s16x8 a, s16x8 b, f32x4 c) {
    return __builtin_amdgcn_mfma_f32_16x16x32_bf16(a, b, c, 0, 0, 0);
}

__device__ __forceinline__ unsigned short f2bf(float f) {
    unsigned u = __float_as_uint(f);
    u += 0x7fffu + ((u >> 16) & 1u);   // RNE
    return (unsigned short)(u >> 16);
}

// ---------------- fp32 -> bf16 convert ----------------
__global__ __launch_bounds__(256) void cvt_bf16_k(const float* __restrict__ in,
                                                  unsigned short* __restrict__ out, int n4) {
    int i = blockIdx.x * 256 + threadIdx.x;
    if (i < n4) {
        float4 v = ((const float4*)in)[i];
        ushort4 o;
        o.x = f2bf(v.x); o.y = f2bf(v.y); o.z = f2bf(v.z); o.w = f2bf(v.w);
        ((ushort4*)out)[i] = o;
    }
}

// ---------------- QKV GEMM: [8192x768] @ [2304x768]^T + bias -> q,k,v [B,H,N,D] bf16 ----------------
__global__ __launch_bounds__(256) void gemm_qkv_k(
    const unsigned short* __restrict__ A,   // xb [8192][768]
    const unsigned short* __restrict__ Bw,  // wqb [2304][768]
    const float* __restrict__ bias,         // [2304]
    unsigned short* __restrict__ qs, unsigned short* __restrict__ ks,
    unsigned short* __restrict__ vs)
{
    __shared__ unsigned short Al[128 * 32];
    __shared__ unsigned short Bl[128 * 32];
    const int tid = threadIdx.x, wv = tid >> 6, ln = tid & 63;
    const int r = ln & 15, q = ln >> 4;
    const int i0 = blockIdx.y * 128, j0 = blockIdx.x * 128;
    const int wm = (wv & 1) * 64, wn = (wv >> 1) * 64;
    const int srow = tid >> 2, scol = (tid & 3) * 8;   // 64 rows x 32 cols per pass, 2 passes
    f32x4 acc[4][4] = {};
    for (int kb = 0; kb < 768; kb += 32) {
        s16x8 av0 = *(const s16x8*)(A  + (size_t)(i0 + srow) * 768 + kb + scol);
        s16x8 av1 = *(const s16x8*)(A  + (size_t)(i0 + srow + 64) * 768 + kb + scol);
        s16x8 bv0 = *(const s16x8*)(Bw + (size_t)(j0 + srow) * 768 + kb + scol);
        s16x8 bv1 = *(const s16x8*)(Bw + (size_t)(j0 + srow + 64) * 768 + kb + scol);
        __syncthreads();
        *(s16x8*)(Al + srow * 32 + scol)        = av0;
        *(s16x8*)(Al + (srow + 64) * 32 + scol) = av1;
        *(s16x8*)(Bl + srow * 32 + scol)        = bv0;
        *(s16x8*)(Bl + (srow + 64) * 32 + scol) = bv1;
        __syncthreads();
        s16x8 af[4], bf[4];
#pragma unroll
        for (int mt = 0; mt < 4; mt++) af[mt] = *(const s16x8*)(Al + (wm + mt * 16 + r) * 32 + q * 8);
#pragma unroll
        for (int nt = 0; nt < 4; nt++) bf[nt] = *(const s16x8*)(Bl + (wn + nt * 16 + r) * 32 + q * 8);
#pragma unroll
        for (int mt = 0; mt < 4; mt++)
#pragma unroll
            for (int nt = 0; nt < 4; nt++)
                acc[mt][nt] = mfma16(af[mt], bf[nt], acc[mt][nt]);
    }
#pragma unroll
    for (int nt = 0; nt < 4; nt++) {
        int j = j0 + wn + nt * 16 + r;                 // column in [0,2304): (t,h,d)
        int t = (j >= 1536) ? 2 : (j >= 768 ? 1 : 0);
        int rem = j - t * 768;
        int h = rem >> 6, d = rem & 63;
        float bb = bias[j];
#pragma unroll
        for (int mt = 0; mt < 4; mt++) {
#pragma unroll
            for (int rr = 0; rr < 4; rr++) {
                int i = i0 + wm + mt * 16 + q * 4 + rr;  // row = (b,n)
                int bidx = i >> 10, n = i & 1023;
                float val = acc[mt][nt][rr] + bb;
                size_t off = (((size_t)bidx * 12 + h) * 1024 + n) * 64 + d;
                if (t == 0)      qs[off] = f2bf(val * QK_SCALE);  // fold softmax scale+log2e into q
                else if (t == 1) ks[off] = f2bf(val);
                else             vs[off] = f2bf(val);
            }
        }
    }
}

// ---------------- v [BH][N][D] -> vT [BH][D][N] ----------------
__global__ __launch_bounds__(256) void transpose_v_k(const unsigned short* __restrict__ vs,
                                                     unsigned short* __restrict__ vT)
{
    __shared__ unsigned short t[64][65];
    const int tid = threadIdx.x;
    const int bh = blockIdx.x;
    const int n0 = blockIdx.y * 64;
    const unsigned short* src = vs + ((size_t)bh * 1024 + n0) * 64;
#pragma unroll
    for (int i = 0; i < 4; i++) {
        int id4 = tid + i * 256;
        int row = id4 >> 4, c4 = (id4 & 15) * 4;
        ushort4 v = *(const ushort4*)(src + row * 64 + c4);
        t[row][c4 + 0] = v.x; t[row][c4 + 1] = v.y; t[row][c4 + 2] = v.z; t[row][c4 + 3] = v.w;
    }
    __syncthreads();
#pragma unroll
    for (int i = 0; i < 4; i++) {
        int id4 = tid + i * 256;
        int d = id4 >> 4, c4 = (id4 & 15) * 4;
        ushort4 o;
        o.x = t[c4 + 0][d]; o.y = t[c4 + 1][d]; o.z = t[c4 + 2][d]; o.w = t[c4 + 3][d];
        *(ushort4*)(vT + ((size_t)bh * 64 + d) * 1024 + n0 + c4) = o;
    }
}

// ---------------- attention pass 1 (single sweep, m-major lanes): invL + cross-moment C ----------------
// Swapped QK^T: sc = mfma(K, Q) -> lane (r,q) reg rr holds S[n = n0+r][m = m0(+16) + q*4+rr].
// Et layout [h(16)][n(16)][m(36 pad)], h-stride 580 shorts: b64 writes 8B-aligned, ~2-way banks.
__global__ __launch_bounds__(256) void attn_stats_k(
    const unsigned short* __restrict__ qs, const unsigned short* __restrict__ ks,
    float* __restrict__ Lbuf, float* __restrict__ Cmat)
{
    __shared__ unsigned short Et[16 * 580];
    __shared__ float invLt[16][17];
    __shared__ float Cred[256];
    const int tid = threadIdx.x, wv = tid >> 6, ln = tid & 63;
    const int r = ln & 15, q = ln >> 4;
    const int b = blockIdx.x >> 6, n0 = (blockIdx.x & 63) * 16;
    const size_t bh0 = (size_t)b * 12;

    for (int i = tid; i < 16 * 580; i += 256) Et[i] = 0;
    for (int i = tid; i < 272; i += 256) (&invLt[0][0])[i] = 0.f;
    Cred[tid] = 0.f;

    s16x8 qf[3][2];
#pragma unroll
    for (int hh = 0; hh < 3; hh++) {
        int h = wv * 3 + hh;
        const unsigned short* qp = qs + ((bh0 + h) * 1024 + n0 + r) * 64 + q * 8;
        qf[hh][0] = *(const s16x8*)qp;
        qf[hh][1] = *(const s16x8*)(qp + 32);
    }
    float rsum[3] = {};
    f32x4 Macc[4] = {};   // per-row moments M[g][h'] for rows n = wv*4 + t
    __syncthreads();      // LDS init visible before first use

    for (int m0 = 0; m0 < 1024; m0 += 32) {
#pragma unroll
        for (int hh = 0; hh < 3; hh++) {
            int h = wv * 3 + hh;
            const unsigned short* kp = ks + (bh0 + h) * 65536;
            f32x4 sc0 = {0,0,0,0}, sc1 = {0,0,0,0};
#pragma unroll
            for (int s = 0; s < 2; s++) {
                s16x8 k0 = *(const s16x8*)(kp + (size_t)(m0 + r) * 64 + s * 32 + q * 8);
                s16x8 k1 = *(const s16x8*)(kp + (size_t)(m0 + 16 + r) * 64 + s * 32 + q * 8);
                sc0 = mfma16(k0, qf[hh][s], sc0);   // swapped: m-major lane layout
                sc1 = mfma16(k1, qf[hh][s], sc1);
            }
            ushort4 p0, p1;
            float e;
            e = exp2f(sc0[0]); rsum[hh] += e; p0.x = f2bf(e);
            e = exp2f(sc0[1]); rsum[hh] += e; p0.y = f2bf(e);
            e = exp2f(sc0[2]); rsum[hh] += e; p0.z = f2bf(e);
            e = exp2f(sc0[3]); rsum[hh] += e; p0.w = f2bf(e);
            e = exp2f(sc1[0]); rsum[hh] += e; p1.x = f2bf(e);
            e = exp2f(sc1[1]); rsum[hh] += e; p1.y = f2bf(e);
            e = exp2f(sc1[2]); rsum[hh] += e; p1.z = f2bf(e);
            e = exp2f(sc1[3]); rsum[hh] += e; p1.w = f2bf(e);
            unsigned short* eb = Et + h * 580 + r * 36 + q * 4;
            *(ushort4*)(eb)      = p0;    // m = q*4..q*4+3
            *(ushort4*)(eb + 16) = p1;    // m = 16+q*4..
        }
        __syncthreads();
        // M[g][h'] += E E^T over this 32-m slab (A==B frag: rows=h via lane r, k=m via q*8)
#pragma unroll
        for (int t = 0; t < 4; t++) {
            const unsigned short* ep = Et + r * 580 + (wv * 4 + t) * 36 + q * 8;
            union { uint2 u[2]; s16x8 v; } U;
            U.u[0] = *(const uint2*)ep;
            U.u[1] = *(const uint2*)(ep + 4);
            Macc[t] = mfma16(U.v, U.v, Macc[t]);
        }
        __syncthreads();
    }
    // finalize invl: reduce over q (2 steps), lane q==0 holds sum for n = n0 + r
#pragma unroll
    for (int hh = 0; hh < 3; hh++) {
        float v = rsum[hh];
        v += __shfl_xor(v, 16, 64);
        v += __shfl_xor(v, 32, 64);
        float iv = 1.0f / v;
        if (q == 0) {
            Lbuf[(bh0 + wv * 3 + hh) * 1024 + n0 + r] = iv;
            invLt[r][wv * 3 + hh] = iv;
        }
    }
    __syncthreads();
    // C_lane[g=q*4+rr][h'=r] += invl_g[n] * invl_h'[n] * M[n]
    float cl[4] = {0.f, 0.f, 0.f, 0.f};
#pragma unroll
    for (int t = 0; t < 4; t++) {
        int n = wv * 4 + t;
        float ih = invLt[n][r];
#pragma unroll
        for (int rr = 0; rr < 4; rr++)
            cl[rr] += invLt[n][q * 4 + rr] * ih * Macc[t][rr];
    }
    // block-level reduce in LDS, then one global atomic per slot per block
#pragma unroll
    for (int rr = 0; rr < 4; rr++)
        atomicAdd(&Cred[(q * 4 + rr) * 16 + r], cl[rr]);
    __syncthreads();
    if (Cred[tid] != 0.f) atomicAdd(&Cmat[tid], Cred[tid]);
}

// ---------------- BN stats finalize -> folded W2 (bf16, padded [16][32]) and c2 ----------------
__global__ void bn_stats_k(const float* __restrict__ Cmat,
                           const float* __restrict__ w_re, const float* __restrict__ b_re,
                           const float* __restrict__ gamma, const float* __restrict__ beta,
                           unsigned short* __restrict__ W2, float* __restrict__ c2)
{
    __shared__ float Cs[12][12];
    int tid = threadIdx.x;
    if (tid < 144) Cs[tid / 12][tid % 12] = Cmat[(tid / 12) * 16 + (tid % 12)];
    __syncthreads();
    if (tid < 16) {
        for (int hc = 0; hc < 32; hc++) W2[tid * 32 + hc] = 0;
        if (tid >= 12) c2[tid] = 0.f;
    }
    if (tid < 12) {
        const float S1 = 8192.f;        // sum of P over all (b,n,m) per head (rows sum to 1)
        const float cnt = 8388608.f;    // B*N*N
        float wg[12];
        for (int h = 0; h < 12; h++) wg[h] = w_re[tid * 12 + h];
        float bg = b_re[tid];
        float sw = 0.f;
        for (int h = 0; h < 12; h++) sw += wg[h];
        float mean = sw * (S1 / cnt) + bg;
        float q2 = 0.f;
        for (int h = 0; h < 12; h++)
            for (int h2 = 0; h2 < 12; h2++) q2 += wg[h] * wg[h2] * Cs[h][h2];
        float sumsq = q2 + 2.f * bg * sw * S1 + cnt * bg * bg;
        float var = sumsq / cnt - mean * mean;
        float scale = gamma[tid] * rsqrtf(var + 1e-5f);
        c2[tid] = beta[tid] - mean * scale + scale * bg;
        for (int h = 0; h < 12; h++) W2[tid * 32 + h] = f2bf(scale * wg[h]);
    }
}

// ---------------- pass 2: scores -> P -> mix(W2)+c2 -> write attn + PV -> out_head ----------------
__global__ __launch_bounds__(256) void attn_out_k(
    const unsigned short* __restrict__ qs, const unsigned short* __restrict__ ks,
    const unsigned short* __restrict__ vT, const float* __restrict__ Lbuf,
    const unsigned short* __restrict__ W2, const float* __restrict__ c2,
    float* __restrict__ attnO, unsigned short* __restrict__ oh)
{
    __shared__ unsigned short P[512][32];   // [pt][h-slot(32)], hblock XOR-swizzled by pt
    __shared__ unsigned short AT[12 * 648]; // attn tile [g][n(16)][m(40 pad)], g-stride 648
    const int tid = threadIdx.x, wv = tid >> 6, ln = tid & 63;
    const int r = ln & 15, q = ln >> 4;
    const int b = blockIdx.x >> 6, n0 = (blockIdx.x & 63) * 16;
    const size_t bh0 = (size_t)b * 12;

    for (int i = tid; i < 512 * 32; i += 256) ((unsigned short*)P)[i] = 0;

    s16x8 qf[3][2];
    float invl[3][4];
#pragma unroll
    for (int hh = 0; hh < 3; hh++) {
        int h = wv * 3 + hh;
        const unsigned short* qp = qs + ((bh0 + h) * 1024 + n0 + r) * 64 + q * 8;
        qf[hh][0] = *(const s16x8*)qp;
        qf[hh][1] = *(const s16x8*)(qp + 32);
#pragma unroll
        for (int rr = 0; rr < 4; rr++)
            invl[hh][rr] = Lbuf[(bh0 + h) * 1024 + n0 + q * 4 + rr];
    }
    s16x8 w2f = *(const s16x8*)(W2 + r * 32 + q * 8);  // [g = lane&15][h = q*8+j]
    const float c2v = c2[r];                           // mix output g = r now
    f32x4 pv[3][4] = {};
    __syncthreads();

    for (int m0 = 0; m0 < 1024; m0 += 32) {
        // scores + P scatter (unswapped: proven layout/swizzle)
#pragma unroll
        for (int hh = 0; hh < 3; hh++) {
            int h = wv * 3 + hh;
            const unsigned short* kp = ks + (bh0 + h) * 1024 * 64;
            f32x4 sc0 = {0,0,0,0}, sc1 = {0,0,0,0};
#pragma unroll
            for (int s = 0; s < 2; s++) {
                s16x8 k0 = *(const s16x8*)(kp + (size_t)(m0 + r) * 64 + s * 32 + q * 8);
                s16x8 k1 = *(const s16x8*)(kp + (size_t)(m0 + 16 + r) * 64 + s * 32 + q * 8);
                sc0 = mfma16(qf[hh][s], k0, sc0);
                sc1 = mfma16(qf[hh][s], k1, sc1);
            }
            int hb = h >> 3, hl = h & 7;
#pragma unroll
            for (int rr = 0; rr < 4; rr++) {
                int pt0 = (q * 4 + rr) * 32 + r;
                int pt1 = pt0 + 16;
                P[pt0][((hb + pt0) & 3) * 8 + hl] = f2bf(exp2f(sc0[rr]) * invl[hh][rr]);
                P[pt1][((hb + pt1) & 3) * 8 + hl] = f2bf(exp2f(sc1[rr]) * invl[hh][rr]);
            }
        }
        __syncthreads();
        // mix (swapped): D = mfma(P, W2) -> lane reg rr holds attn_norm[pt = ptb+q*4+rr][g = r]
        // -> float4 global store + b64 AT store (4 consecutive m at fixed g)
#pragma unroll
        for (int t = 0; t < 8; t++) {
            int ptb = wv * 128 + t * 16;
            int pt = ptb + r;
            s16x8 pf = *(const s16x8*)(&P[pt][((q + pt) & 3) * 8]);
            f32x4 d = mfma16(pf, w2f, f32x4{0, 0, 0, 0});
            int n = wv * 4 + (t >> 1);
            int mb = (t & 1) * 16 + q * 4;
            if (r < 12) {
                float4 st;
                st.x = d[0] + c2v; st.y = d[1] + c2v;
                st.z = d[2] + c2v; st.w = d[3] + c2v;
                *(float4*)(attnO + ((bh0 + r) * 1024 + n0 + n) * 1024 + m0 + mb) = st;
                ushort4 a4;
                a4.x = f2bf(st.x); a4.y = f2bf(st.y); a4.z = f2bf(st.z); a4.w = f2bf(st.w);
                *(ushort4*)(AT + r * 648 + n * 40 + mb) = a4;
            }
        }
        __syncthreads();
        // PV: out[g][n][d] += attn_norm @ v  (vT gives contiguous B-frags)
#pragma unroll
        for (int hh = 0; hh < 3; hh++) {
            int g = wv * 3 + hh;
            s16x8 af = *(const s16x8*)(AT + g * 648 + r * 40 + q * 8);
            const unsigned short* vp = vT + (bh0 + g) * 64 * 1024;
#pragma unroll
            for (int dt = 0; dt < 4; dt++) {
                s16x8 vf = *(const s16x8*)(vp + (size_t)(dt * 16 + r) * 1024 + m0 + q * 8);
                pv[hh][dt] = mfma16(af, vf, pv[hh][dt]);
            }
        }
        __syncthreads();
    }
    // epilogue: out_head bf16 [b][n][h*64+d]  (proj-ready layout)
#pragma unroll
    for (int hh = 0; hh < 3; hh++) {
        int h = wv * 3 + hh;
#pragma unroll
        for (int dt = 0; dt < 4; dt++) {
#pragma unroll
            for (int rr = 0; rr < 4; rr++) {
                int n = n0 + q * 4 + rr;
                oh[((size_t)b * 1024 + n) * 768 + h * 64 + dt * 16 + r] = f2bf(pv[hh][dt][rr]);
            }
        }
    }
}

// ---------------- proj GEMM: oh [8192x768] @ w_proj^T + bias -> out fp32 ----------------
__global__ __launch_bounds__(256) void gemm_proj_k(
    const unsigned short* __restrict__ A,   // oh [8192][768]
    const unsigned short* __restrict__ Bw,  // wpb [768][768]
    const float* __restrict__ bias, float* __restrict__ Co)
{
    __shared__ unsigned short Al[128 * 32];
    __shared__ unsigned short Bl[128 * 32];
    const int tid = threadIdx.x, wv = tid >> 6, ln = tid & 63;
    const int r = ln & 15, q = ln >> 4;
    const int i0 = blockIdx.y * 128, j0 = blockIdx.x * 128;
    const int wm = (wv & 1) * 64, wn = (wv >> 1) * 64;
    const int srow = tid >> 2, scol = (tid & 3) * 8;   // full 128x32 tile coverage
    f32x4 acc[4][4] = {};
    for (int kb = 0; kb < 768; kb += 32) {
        s16x8 av0 = *(const s16x8*)(A  + (size_t)(i0 + srow) * 768 + kb + scol);
        s16x8 av1 = *(const s16x8*)(A  + (size_t)(i0 + srow + 64) * 768 + kb + scol);
        s16x8 bv0 = *(const s16x8*)(Bw + (size_t)(j0 + srow) * 768 + kb + scol);
        s16x8 bv1 = *(const s16x8*)(Bw + (size_t)(j0 + srow + 64) * 768 + kb + scol);
        __syncthreads();
        *(s16x8*)(Al + srow * 32 + scol)        = av0;
        *(s16x8*)(Al + (srow + 64) * 32 + scol) = av1;
        *(s16x8*)(Bl + srow * 32 + scol)        = bv0;
        *(s16x8*)(Bl + (srow + 64) * 32 + scol) = bv1;
        __syncthreads();
        s16x8 af[4], bf[4];
#pragma unroll
        for (int mt = 0; mt < 4; mt++) af[mt] = *(const s16x8*)(Al + (wm + mt * 16 + r) * 32 + q * 8);
#pragma unroll
        for (int nt = 0; nt < 4; nt++) bf[nt] = *(const s16x8*)(Bl + (wn + nt * 16 + r) * 32 + q * 8);
#pragma unroll
        for (int mt = 0; mt < 4; mt++)
#pragma unroll
            for (int nt = 0; nt < 4; nt++)
                acc[mt][nt] = mfma16(af[mt], bf[nt], acc[mt][nt]);
    }
#pragma unroll
    for (int nt = 0; nt < 4; nt++) {
        int j = j0 + wn + nt * 16 + r;
        float bb = bias[j];
#pragma unroll
        for (int mt = 0; mt < 4; mt++) {
#pragma unroll
            for (int rr = 0; rr < 4; rr++) {
                int i = i0 + wm + mt * 16 + q * 4 + rr;
                Co[(size_t)i * 768 + j] = acc[mt][nt][rr] + bb;
            }
        }
    }
}

extern "C" void kernel_launch(void* const* d_in, const int* in_sizes, int n_in,
                              void* d_out, int out_size, void* d_ws, size_t ws_size,
                              hipStream_t stream)
{
    const float* x      = (const float*)d_in[0];
    const float* w_qkv  = (const float*)d_in[1];
    const float* b_qkv  = (const float*)d_in[2];
    const float* w_re   = (const float*)d_in[3];
    const float* b_re   = (const float*)d_in[4];
    const float* gamma  = (const float*)d_in[5];
    const float* beta   = (const float*)d_in[6];
    const float* w_proj = (const float*)d_in[7];
    const float* b_proj = (const float*)d_in[8];

    float* outp  = (float*)d_out;
    float* attnp = outp + 6291456;   // out (8,1024,768) then attn (8,12,1024,1024)

    char* ws = (char*)d_ws;
    unsigned short* xb  = (unsigned short*)(ws);              // 12.58 MB (reused as oh later)
    unsigned short* wqb = (unsigned short*)(ws + 12582912);   // 3.54 MB
    unsigned short* wpb = (unsigned short*)(ws + 16121856);   // 1.18 MB
    unsigned short* qs  = (unsigned short*)(ws + 17301504);   // 12.58 MB
    unsigned short* ks  = (unsigned short*)(ws + 29884416);   // 12.58 MB
    unsigned short* vs  = (unsigned short*)(ws + 42467328);   // 12.58 MB
    unsigned short* vT  = (unsigned short*)(ws + 55050240);   // 12.58 MB
    float* Lbuf         = (float*)(ws + 67633152);            // 393 KB (invL)
    float* Cmat         = (float*)(ws + 68026368);            // 1 KB
    unsigned short* W2  = (unsigned short*)(ws + 68027392);   // 1 KB
    float* c2           = (float*)(ws + 68028416);            // 64 B
    unsigned short* oh  = xb;  // out_head overlays xb (xb dead after QKV GEMM)

    hipMemsetAsync(Cmat, 0, 1024, stream);
    cvt_bf16_k<<<6144, 256, 0, stream>>>(x,      xb,  1572864);
    cvt_bf16_k<<<1728, 256, 0, stream>>>(w_qkv,  wqb, 442368);
    cvt_bf16_k<<<576,  256, 0, stream>>>(w_proj, wpb, 147456);
    gemm_qkv_k<<<dim3(18, 64), 256, 0, stream>>>(xb, wqb, b_qkv, qs, ks, vs);
    transpose_v_k<<<dim3(96, 16), 256, 0, stream>>>(vs, vT);
    attn_stats_k<<<512, 256, 0, stream>>>(qs, ks, Lbuf, Cmat);
    bn_stats_k<<<1, 256, 0, stream>>>(Cmat, w_re, b_re, gamma, beta, W2, c2);
    attn_out_k<<<512, 256, 0, stream>>>(qs, ks, vT, Lbuf, W2, c2, attnp, oh);
    gemm_proj_k<<<dim3(6, 64), 256, 0, stream>>>(oh, wpb, b_proj, outp);
}